// Round 1
// baseline (1041.019 us; speedup 1.0000x reference)
//
#include <hip/hip_runtime.h>
#include <hip/hip_bf16.h>

#define NN 50000
#define NE 800000
#define DD 128

typedef unsigned int u32;

struct GemmArgs {
  const float* A[3];
  const float* W[3];
  const float* Bias[3];
  u32* H[3];
  const float* curv;
  int astride;
};

struct AggArgs {
  const u32* H[3];
  float* O[3];
  const int* row_start;
  const int* esrc;
  const float* curv;
  int ostride;
};

__device__ __forceinline__ u32 f2bf(float x){
  u32 u = __float_as_uint(x);
  return (u + 0x7fffu + ((u >> 16) & 1u)) >> 16;   // RNE bf16
}

// ---------------- CSR build ----------------
__global__ void k_hist(const int* __restrict__ dst, int* __restrict__ cnt){
  int i = blockIdx.x*256 + threadIdx.x;
  if (i < NE) atomicAdd(&cnt[dst[i]], 1);
}

__global__ __launch_bounds__(1024) void k_scan(const int* __restrict__ cnt,
                                               int* __restrict__ row_start,
                                               int* __restrict__ cursor){
  __shared__ int wsum[16];
  __shared__ int carry;
  const int t = threadIdx.x, lane = t & 63, wid = t >> 6;
  if (t == 0) carry = 0;
  __syncthreads();
  for (int base = 0; base < NN; base += 1024){
    int i = base + t;
    int v = (i < NN) ? cnt[i] : 0;
    int incl = v;
    #pragma unroll
    for (int off = 1; off < 64; off <<= 1){
      int u = __shfl_up(incl, off, 64);
      if (lane >= off) incl += u;
    }
    if (lane == 63) wsum[wid] = incl;
    __syncthreads();
    if (wid == 0){
      int w = (lane < 16) ? wsum[lane] : 0;
      #pragma unroll
      for (int off = 1; off < 16; off <<= 1){
        int u = __shfl_up(w, off, 64);
        if (lane >= off) w += u;
      }
      if (lane < 16) wsum[lane] = w;
    }
    __syncthreads();
    int woff = (wid > 0) ? wsum[wid-1] : 0;
    int excl = carry + woff + (incl - v);
    if (i < NN){ row_start[i] = excl; cursor[i] = excl; }
    __syncthreads();
    if (t == 0) carry += wsum[15];
    __syncthreads();
  }
  if (t == 0) row_start[NN] = carry;
}

__global__ void k_scatter(const int* __restrict__ src, const int* __restrict__ dst,
                          int* __restrict__ cursor, int* __restrict__ esrc){
  int i = blockIdx.x*256 + threadIdx.x;
  if (i < NE){
    int d = dst[i];
    int p = atomicAdd(&cursor[d], 1);
    esrc[p] = src[i];
  }
}

// ---------------- fused pre-transform + GEMM (h = pre(A) @ W^T + b [+postnorm]) ----
// block 256, tile 64 rows x 128 cols, K=128.  m: 0=euclid 1=hyperbolic 2=spherical
__global__ __launch_bounds__(256,1) void k_gemm(GemmArgs ga){
  const int m = blockIdx.y;
  const float* __restrict__ A    = ga.A[m];
  const float* __restrict__ Wg   = ga.W[m];
  const float* __restrict__ Bias = ga.Bias[m];
  u32* __restrict__ H = ga.H[m];
  const int astride = ga.astride;
  const int row0 = blockIdx.x * 64;
  const int t = threadIdx.x;

  __shared__ float As[64][132];       // natural [r][k], stride 132 -> 2-way (free)
  __shared__ float4 Wl[128*32];       // [c][k/4] with kb ^= (c>>3)&7 swizzle -> 2-way (free)

  {
    const float4* Wg4 = (const float4*)Wg;
    #pragma unroll
    for (int it = 0; it < 16; ++it){
      int idx = it*256 + t;
      int c = idx >> 5, kb = idx & 31;
      Wl[(c<<5) | (kb ^ ((c>>3)&7))] = Wg4[idx];
    }
  }

  float sc = 1.0f;
  if (m == 1) sc = sqrtf(*ga.curv);

  // stage A; each iteration covers 8 full rows (32 consecutive lanes = 1 row),
  // so row norms for the pre-transform come from a half-wave shuffle reduce.
  #pragma unroll
  for (int it = 0; it < 8; ++it){
    int idx = it*256 + t;
    int r = idx >> 5, kb = idx & 31;
    int grow = row0 + r;
    float4 a = make_float4(0.f,0.f,0.f,0.f);
    if (grow < NN) a = *((const float4*)(A + (long)grow*astride + (kb<<2)));
    if (m != 0){
      float p = a.x*a.x + a.y*a.y + a.z*a.z + a.w*a.w;
      #pragma unroll
      for (int off = 1; off < 32; off <<= 1) p += __shfl_xor(p, off, 64);
      float nrm = sqrtf(p);
      float s;
      if (m == 1){   // log-map at origin: (2/sc)*artanh(sc*|y|)/|y|
        float x = sc * nrm;
        s = (nrm > 1e-30f) ? (logf((1.f + x) / (1.f - x)) / (sc * nrm)) : 2.f;
      } else {       // l2norm
        s = 1.f / fmaxf(nrm, 1e-12f);
      }
      a.x *= s; a.y *= s; a.z *= s; a.w *= s;
    }
    *((float4*)&As[r][kb<<2]) = a;
  }
  __syncthreads();

  const int cg = t & 15, rg = t >> 4;
  const int r0 = rg << 2, c0 = cg << 3;
  float acc[4][8];
  #pragma unroll
  for (int i=0;i<4;++i)
    #pragma unroll
    for (int j=0;j<8;++j) acc[i][j] = 0.f;

  #pragma unroll 4
  for (int kb = 0; kb < 32; ++kb){
    float4 av[4];
    #pragma unroll
    for (int i=0;i<4;++i) av[i] = *((const float4*)&As[r0+i][kb<<2]);
    const int skb = kb ^ (cg & 7);
    float4 wv[8];
    #pragma unroll
    for (int j=0;j<8;++j) wv[j] = Wl[((c0+j)<<5) | skb];
    #pragma unroll
    for (int i=0;i<4;++i){
      #pragma unroll
      for (int j=0;j<8;++j){
        acc[i][j] += av[i].x*wv[j].x;
        acc[i][j] += av[i].y*wv[j].y;
        acc[i][j] += av[i].z*wv[j].z;
        acc[i][j] += av[i].w*wv[j].w;
      }
    }
  }

  #pragma unroll
  for (int j=0;j<8;++j){
    float bv = Bias[c0+j];
    #pragma unroll
    for (int i=0;i<4;++i) acc[i][j] += bv;
  }

  if (m == 2){   // spherical: l2norm on output rows (16 lanes share a row)
    #pragma unroll
    for (int i=0;i<4;++i){
      float p = 0.f;
      #pragma unroll
      for (int j=0;j<8;++j) p += acc[i][j]*acc[i][j];
      #pragma unroll
      for (int off=1; off<16; off<<=1) p += __shfl_xor(p, off, 64);
      float inv = 1.f / fmaxf(sqrtf(p), 1e-12f);
      #pragma unroll
      for (int j=0;j<8;++j) acc[i][j] *= inv;
    }
  }

  #pragma unroll
  for (int i=0;i<4;++i){
    int grow = row0 + r0 + i;
    if (grow < NN){
      uint4 pk;
      pk.x = f2bf(acc[i][0]) | (f2bf(acc[i][1]) << 16);
      pk.y = f2bf(acc[i][2]) | (f2bf(acc[i][3]) << 16);
      pk.z = f2bf(acc[i][4]) | (f2bf(acc[i][5]) << 16);
      pk.w = f2bf(acc[i][6]) | (f2bf(acc[i][7]) << 16);
      *((uint4*)(H + (long)grow*64 + (c0>>1))) = pk;
    }
  }
}

// ---------------- mean-aggregate + post-transform; one wave per (node, manifold) ---
__global__ __launch_bounds__(256) void k_agg(AggArgs aa){
  const int lane = threadIdx.x & 63;
  const int gw = blockIdx.x*4 + (threadIdx.x >> 6);
  if (gw >= 3*NN) return;
  const int node = gw / 3;
  const int m = gw - node*3;
  const int e0 = aa.row_start[node];
  const int e1 = aa.row_start[node+1];
  const u32* __restrict__ h = aa.H[m];
  const int* __restrict__ esrc = aa.esrc;
  float a0 = 0.f, a1 = 0.f;          // features 2*lane, 2*lane+1
  for (int e = e0; e < e1; ++e){
    int s = esrc[e];
    u32 v = h[(long)s*64 + lane];    // 256B coalesced bf16 row gather
    a0 += __uint_as_float(v << 16);
    a1 += __uint_as_float(v & 0xffff0000u);
  }
  float inv = 1.f / fmaxf((float)(e1 - e0), 1.f);
  a0 *= inv; a1 *= inv;
  if (m == 0){                        // leaky_relu 0.2
    a0 = (a0 > 0.f) ? a0 : 0.2f*a0;
    a1 = (a1 > 0.f) ? a1 : 0.2f*a1;
  } else {
    float p = a0*a0 + a1*a1;
    #pragma unroll
    for (int off=1; off<64; off<<=1) p += __shfl_xor(p, off, 64);
    float nrm = sqrtf(p);
    float s;
    if (m == 1){                      // exp-map at origin: tanh(sc*|v|/2)/(sc*|v|)
      float scv = sqrtf(*aa.curv);
      float x = scv * nrm;
      s = (nrm > 1e-30f) ? (tanhf(0.5f*x) / x) : 0.5f;
    } else {                          // l2norm
      s = 1.f / fmaxf(nrm, 1e-12f);
    }
    a0 *= s; a1 *= s;
  }
  *((float2*)(aa.O[m] + (long)node*aa.ostride + (lane<<1))) = make_float2(a0, a1);
}

extern "C" void kernel_launch(void* const* d_in, const int* in_sizes, int n_in,
                              void* d_out, int out_size, void* d_ws, size_t ws_size,
                              hipStream_t stream){
  (void)in_sizes; (void)n_in; (void)out_size; (void)ws_size;
  const int*   src    = (const int*)  d_in[0];
  const int*   dst    = (const int*)  d_in[1];
  const float* e_emb  = (const float*)d_in[2];
  const float* b_emb  = (const float*)d_in[3];
  const float* s_emb  = (const float*)d_in[4];
  const float* e_W    = (const float*)d_in[5];
  const float* e_b    = (const float*)d_in[6];
  const float* b_W    = (const float*)d_in[7];
  const float* b_b    = (const float*)d_in[8];
  const float* s_W    = (const float*)d_in[9];
  const float* s_b    = (const float*)d_in[10];
  const float* b_curv = (const float*)d_in[11];
  float* out = (float*)d_out;

  char* ws = (char*)d_ws;
  size_t off = 0;
  auto alloc = [&](size_t bytes) -> void* {
    void* p = (void*)(ws + off);
    off += (bytes + 255) & ~(size_t)255;
    return p;
  };
  int* cnt       = (int*)alloc((size_t)NN*4);
  int* row_start = (int*)alloc((size_t)(NN+1)*4);
  int* cursor    = (int*)alloc((size_t)NN*4);
  int* esrc      = (int*)alloc((size_t)NE*4);
  u32* h0 = (u32*)alloc((size_t)NN*64*4);
  u32* h1 = (u32*)alloc((size_t)NN*64*4);
  u32* h2 = (u32*)alloc((size_t)NN*64*4);

  hipMemsetAsync(cnt, 0, (size_t)NN*4, stream);
  k_hist   <<<NE/256, 256, 0, stream>>>(dst, cnt);
  k_scan   <<<1, 1024, 0, stream>>>(cnt, row_start, cursor);
  k_scatter<<<NE/256, 256, 0, stream>>>(src, dst, cursor, esrc);

  GemmArgs g;
  AggArgs  a;
  g.curv = b_curv;
  a.H[0]=h0; a.H[1]=h1; a.H[2]=h2;
  a.O[0]=out; a.O[1]=out+DD; a.O[2]=out+2*DD;
  a.row_start=row_start; a.esrc=esrc; a.curv=b_curv; a.ostride=3*DD;

  dim3 ggrid((NN+63)/64, 3);

  // ----- layer 0 (reads pristine inputs, writes embeddings into d_out slots) -----
  g.astride = DD;
  g.A[0]=e_emb; g.A[1]=b_emb; g.A[2]=s_emb;
  g.W[0]=e_W;   g.W[1]=b_W;   g.W[2]=s_W;
  g.Bias[0]=e_b; g.Bias[1]=b_b; g.Bias[2]=s_b;
  g.H[0]=h0; g.H[1]=h1; g.H[2]=h2;
  k_gemm<<<ggrid, 256, 0, stream>>>(g);
  k_agg <<<(3*NN)/4, 256, 0, stream>>>(a);

  // ----- layer 1 (reads d_out strided, overwrites d_out) -----
  g.astride = 3*DD;
  g.A[0]=out; g.A[1]=out+DD; g.A[2]=out+2*DD;
  g.W[0]=e_W+DD*DD; g.W[1]=b_W+DD*DD; g.W[2]=s_W+DD*DD;
  g.Bias[0]=e_b+DD; g.Bias[1]=b_b+DD; g.Bias[2]=s_b+DD;
  k_gemm<<<ggrid, 256, 0, stream>>>(g);
  k_agg <<<(3*NN)/4, 256, 0, stream>>>(a);
}

// Round 2
// 619.285 us; speedup vs baseline: 1.6810x; 1.6810x over previous
//
#include <hip/hip_runtime.h>
#include <hip/hip_bf16.h>

#define NN 50000
#define NE 800000
#define DD 128

typedef unsigned int u32;
typedef __attribute__((ext_vector_type(8))) short short8;   // 8 bf16 = 4 VGPRs
typedef __attribute__((ext_vector_type(4))) float f32x4;
typedef __attribute__((ext_vector_type(4))) u32 u32x4;

struct GemmArgs {
  const float* A[3];
  const float* W[3];
  const float* Bias[3];
  u32* H;                 // manifold m at H + m*NN*64
  const float* curv;
  int astride;
};

struct AggArgs {
  const u32* H;
  float* O;
  const int* row_start;
  const int* esrc;
  const float* curv;
};

__device__ __forceinline__ u32 f2bf(float x){
  u32 u = __float_as_uint(x);
  return (u + 0x7fffu + ((u >> 16) & 1u)) >> 16;   // RNE bf16
}
__device__ __forceinline__ float blo(u32 v){ return __uint_as_float(v << 16); }
__device__ __forceinline__ float bhi(u32 v){ return __uint_as_float(v & 0xffff0000u); }

// ---------------- CSR build ----------------
__global__ void k_hist(const int* __restrict__ dst, int* __restrict__ cnt){
  int i = blockIdx.x*256 + threadIdx.x;
  if (i < NE) atomicAdd(&cnt[dst[i]], 1);
}

__global__ __launch_bounds__(1024) void k_scan(const int* __restrict__ cnt,
                                               int* __restrict__ row_start,
                                               int* __restrict__ cursor){
  __shared__ int wsum[16];
  __shared__ int carry;
  const int t = threadIdx.x, lane = t & 63, wid = t >> 6;
  if (t == 0) carry = 0;
  __syncthreads();
  for (int base = 0; base < NN; base += 1024){
    int i = base + t;
    int v = (i < NN) ? cnt[i] : 0;
    int incl = v;
    #pragma unroll
    for (int off = 1; off < 64; off <<= 1){
      int u = __shfl_up(incl, off, 64);
      if (lane >= off) incl += u;
    }
    if (lane == 63) wsum[wid] = incl;
    __syncthreads();
    if (wid == 0){
      int w = (lane < 16) ? wsum[lane] : 0;
      #pragma unroll
      for (int off = 1; off < 16; off <<= 1){
        int u = __shfl_up(w, off, 64);
        if (lane >= off) w += u;
      }
      if (lane < 16) wsum[lane] = w;
    }
    __syncthreads();
    int woff = (wid > 0) ? wsum[wid-1] : 0;
    int excl = carry + woff + (incl - v);
    if (i < NN){ row_start[i] = excl; cursor[i] = excl; }
    __syncthreads();
    if (t == 0) carry += wsum[15];
    __syncthreads();
  }
  if (t == 0) row_start[NN] = carry;
}

__global__ void k_scatter(const int* __restrict__ src, const int* __restrict__ dst,
                          int* __restrict__ cursor, int* __restrict__ esrc){
  int i = blockIdx.x*256 + threadIdx.x;
  if (i < NE){
    int d = dst[i];
    int p = atomicAdd(&cursor[d], 1);
    esrc[p] = src[i];
  }
}

// ------------- fused pre-transform + bf16-MFMA GEMM:  h = pre(A) @ W^T + b -------
// block 256 = 4 waves, 256 rows per block (4 stripes of 64), W in registers as
// a-frags (D[c][r] = W * A^T orientation -> lane holds 4 consecutive channels).
__global__ __launch_bounds__(256,2) void k_gemm(GemmArgs ga){
  const int m = blockIdx.y;
  const float* __restrict__ A    = ga.A[m];
  const float* __restrict__ Wg   = ga.W[m];
  const float* __restrict__ Bias = ga.Bias[m];
  u32* __restrict__ H = ga.H + (size_t)m*NN*64;
  const int astride = ga.astride;
  const int row0 = blockIdx.x * 256;
  const int t = threadIdx.x;
  const int lane = t & 63, wv = t >> 6;
  const int rr = lane & 15, quad = lane >> 4;

  __shared__ u32 As[64*68];   // 64 rows x (128 bf16 + 8 pad) -> 2-way banks (free)

  // ---- W (fp32 global) -> 32 bf16 a-frags in registers (128 VGPRs) ----
  // a-frag for (ct,ks): lane holds W[c = ct*16 + rr][k = ks*32 + quad*8 + j]
  short8 wf[8][4];
  #pragma unroll
  for (int ct = 0; ct < 8; ++ct){
    #pragma unroll
    for (int ks = 0; ks < 4; ++ks){
      const float* p = Wg + (ct*16 + rr)*128 + ks*32 + quad*8;
      float4 f0 = *(const float4*)p;
      float4 f1 = *(const float4*)(p + 4);
      u32x4 q;
      q.x = f2bf(f0.x) | (f2bf(f0.y) << 16);
      q.y = f2bf(f0.z) | (f2bf(f0.w) << 16);
      q.z = f2bf(f1.x) | (f2bf(f1.y) << 16);
      q.w = f2bf(f1.z) | (f2bf(f1.w) << 16);
      wf[ct][ks] = __builtin_bit_cast(short8, q);
    }
  }

  float sc = 1.0f;
  if (m == 1) sc = sqrtf(*ga.curv);

  for (int s = 0; s < 4; ++s){
    const int srow = row0 + s*64;
    // ---- stage 64 rows, fused pre-transform, fp32 -> bf16 into LDS ----
    #pragma unroll
    for (int it = 0; it < 8; ++it){
      int idx = it*256 + t;
      int r = idx >> 5, kb = idx & 31;          // 32 consecutive lanes = 1 row
      int grow = srow + r;
      float4 a = make_float4(0.f,0.f,0.f,0.f);
      if (grow < NN) a = *(const float4*)(A + (size_t)grow*astride + (kb<<2));
      if (m != 0){
        float p = a.x*a.x + a.y*a.y + a.z*a.z + a.w*a.w;
        #pragma unroll
        for (int off = 1; off < 32; off <<= 1) p += __shfl_xor(p, off, 64);
        float nrm = sqrtf(p);
        float sca;
        if (m == 1){   // log-map at origin: (2/sc)*artanh(sc*|y|)/|y|
          float x = sc * nrm;
          sca = (nrm > 1e-30f) ? (logf((1.f + x) / (1.f - x)) / (sc * nrm)) : 2.f;
        } else {       // l2norm
          sca = 1.f / fmaxf(nrm, 1e-12f);
        }
        a.x *= sca; a.y *= sca; a.z *= sca; a.w *= sca;
      }
      uint2 w2;
      w2.x = f2bf(a.x) | (f2bf(a.y) << 16);
      w2.y = f2bf(a.z) | (f2bf(a.w) << 16);
      *(uint2*)&As[r*68 + kb*2] = w2;
    }
    __syncthreads();

    // ---- compute: wave wv handles node rows srow + wv*16 + rr ----
    f32x4 acc[8];
    #pragma unroll
    for (int ct = 0; ct < 8; ++ct){ f32x4 z = {0.f,0.f,0.f,0.f}; acc[ct] = z; }

    const u32* bbase = As + (wv*16 + rr)*68;
    #pragma unroll
    for (int ks = 0; ks < 4; ++ks){
      u32x4 bq = *(const u32x4*)(bbase + ks*16 + quad*4);   // 8 bf16, k consecutive
      short8 bf = __builtin_bit_cast(short8, bq);
      #pragma unroll
      for (int ct = 0; ct < 8; ++ct)
        acc[ct] = __builtin_amdgcn_mfma_f32_16x16x32_bf16(wf[ct][ks], bf, acc[ct], 0, 0, 0);
    }

    // ---- epilogue: bias (+ spherical l2norm), bf16 pack, store ----
    #pragma unroll
    for (int ct = 0; ct < 8; ++ct){
      float4 bv = *(const float4*)(Bias + ct*16 + quad*4);
      acc[ct].x += bv.x; acc[ct].y += bv.y; acc[ct].z += bv.z; acc[ct].w += bv.w;
    }
    if (m == 2){
      float p = 0.f;
      #pragma unroll
      for (int ct = 0; ct < 8; ++ct)
        p += acc[ct].x*acc[ct].x + acc[ct].y*acc[ct].y + acc[ct].z*acc[ct].z + acc[ct].w*acc[ct].w;
      p += __shfl_xor(p, 16, 64);
      p += __shfl_xor(p, 32, 64);
      float inv = 1.f / fmaxf(sqrtf(p), 1e-12f);
      #pragma unroll
      for (int ct = 0; ct < 8; ++ct){
        acc[ct].x *= inv; acc[ct].y *= inv; acc[ct].z *= inv; acc[ct].w *= inv;
      }
    }
    int grow = srow + wv*16 + rr;
    if (grow < NN){
      u32* hp = H + (size_t)grow*64 + quad*2;   // channel = ct*16 + quad*4 + reg
      #pragma unroll
      for (int ct = 0; ct < 8; ++ct){
        uint2 pk;
        pk.x = f2bf(acc[ct].x) | (f2bf(acc[ct].y) << 16);
        pk.y = f2bf(acc[ct].z) | (f2bf(acc[ct].w) << 16);
        *(uint2*)(hp + ct*8) = pk;
      }
    }
    __syncthreads();
  }
}

// ------- mean-aggregate + post-transform; one wave per node, 3 manifolds fused ----
__global__ __launch_bounds__(256) void k_agg(AggArgs aa){
  const int lane = threadIdx.x & 63;
  const int node = blockIdx.x*4 + (threadIdx.x >> 6);
  if (node >= NN) return;
  const int e0 = aa.row_start[node];
  const int e1 = aa.row_start[node+1];
  const int* __restrict__ esrc = aa.esrc;
  const u32* __restrict__ h0 = aa.H;
  const u32* __restrict__ h1 = aa.H + (size_t)NN*64;
  const u32* __restrict__ h2 = aa.H + (size_t)2*NN*64;

  float a00=0.f,a01=0.f,a10=0.f,a11=0.f,a20=0.f,a21=0.f;

  for (int base = e0; base < e1; base += 64){
    int n = e1 - base; if (n > 64) n = 64;
    int sv = esrc[min(base + lane, e1 - 1)];   // one coalesced load covers 64 edges
    int j = 0;
    for (; j + 4 <= n; j += 4){                // 12 independent row-loads in flight
      long o0 = (long)__shfl(sv, j    )*64 + lane;
      long o1 = (long)__shfl(sv, j + 1)*64 + lane;
      long o2 = (long)__shfl(sv, j + 2)*64 + lane;
      long o3 = (long)__shfl(sv, j + 3)*64 + lane;
      u32 p00=h0[o0], p01=h1[o0], p02=h2[o0];
      u32 p10=h0[o1], p11=h1[o1], p12=h2[o1];
      u32 p20=h0[o2], p21=h1[o2], p22=h2[o2];
      u32 p30=h0[o3], p31=h1[o3], p32=h2[o3];
      a00 += blo(p00); a01 += bhi(p00); a10 += blo(p01); a11 += bhi(p01); a20 += blo(p02); a21 += bhi(p02);
      a00 += blo(p10); a01 += bhi(p10); a10 += blo(p11); a11 += bhi(p11); a20 += blo(p12); a21 += bhi(p12);
      a00 += blo(p20); a01 += bhi(p20); a10 += blo(p21); a11 += bhi(p21); a20 += blo(p22); a21 += bhi(p22);
      a00 += blo(p30); a01 += bhi(p30); a10 += blo(p31); a11 += bhi(p31); a20 += blo(p32); a21 += bhi(p32);
    }
    for (; j < n; ++j){
      long o = (long)__shfl(sv, j)*64 + lane;
      u32 q0=h0[o], q1=h1[o], q2=h2[o];
      a00 += blo(q0); a01 += bhi(q0); a10 += blo(q1); a11 += bhi(q1); a20 += blo(q2); a21 += bhi(q2);
    }
  }

  float inv = 1.f / (float)max(e1 - e0, 1);
  a00*=inv; a01*=inv; a10*=inv; a11*=inv; a20*=inv; a21*=inv;

  // euclid: leaky_relu(0.2)
  float o00 = (a00 > 0.f) ? a00 : 0.2f*a00;
  float o01 = (a01 > 0.f) ? a01 : 0.2f*a01;
  // hyperbolic exp-map + spherical l2norm need row norms (dual reduction)
  float p1 = a10*a10 + a11*a11;
  float p2 = a20*a20 + a21*a21;
  #pragma unroll
  for (int off = 1; off < 64; off <<= 1){
    p1 += __shfl_xor(p1, off, 64);
    p2 += __shfl_xor(p2, off, 64);
  }
  float n1 = sqrtf(p1);
  float scv = sqrtf(*aa.curv);
  float x = scv * n1;
  float s1 = (n1 > 1e-30f) ? (tanhf(0.5f*x) / x) : 0.5f;
  float s2 = 1.f / fmaxf(sqrtf(p2), 1e-12f);

  float* op = aa.O + (size_t)node*384 + lane*2;
  *(float2*)(op      ) = make_float2(o00, o01);
  *(float2*)(op + 128) = make_float2(a10*s1, a11*s1);
  *(float2*)(op + 256) = make_float2(a20*s2, a21*s2);
}

extern "C" void kernel_launch(void* const* d_in, const int* in_sizes, int n_in,
                              void* d_out, int out_size, void* d_ws, size_t ws_size,
                              hipStream_t stream){
  (void)in_sizes; (void)n_in; (void)out_size; (void)ws_size;
  const int*   src    = (const int*)  d_in[0];
  const int*   dst    = (const int*)  d_in[1];
  const float* e_emb  = (const float*)d_in[2];
  const float* b_emb  = (const float*)d_in[3];
  const float* s_emb  = (const float*)d_in[4];
  const float* e_W    = (const float*)d_in[5];
  const float* e_b    = (const float*)d_in[6];
  const float* b_W    = (const float*)d_in[7];
  const float* b_b    = (const float*)d_in[8];
  const float* s_W    = (const float*)d_in[9];
  const float* s_b    = (const float*)d_in[10];
  const float* b_curv = (const float*)d_in[11];
  float* out = (float*)d_out;

  char* ws = (char*)d_ws;
  size_t off = 0;
  auto alloc = [&](size_t bytes) -> void* {
    void* p = (void*)(ws + off);
    off += (bytes + 255) & ~(size_t)255;
    return p;
  };
  int* cnt       = (int*)alloc((size_t)NN*4);
  int* row_start = (int*)alloc((size_t)(NN+1)*4);
  int* cursor    = (int*)alloc((size_t)NN*4);
  int* esrc      = (int*)alloc((size_t)NE*4);
  u32* h         = (u32*)alloc((size_t)3*NN*64*4);

  hipMemsetAsync(cnt, 0, (size_t)NN*4, stream);
  k_hist   <<<NE/256, 256, 0, stream>>>(dst, cnt);
  k_scan   <<<1, 1024, 0, stream>>>(cnt, row_start, cursor);
  k_scatter<<<NE/256, 256, 0, stream>>>(src, dst, cursor, esrc);

  GemmArgs g;
  g.curv = b_curv;
  g.H = h;
  AggArgs a;
  a.H = h; a.O = out; a.row_start = row_start; a.esrc = esrc; a.curv = b_curv;

  dim3 ggrid((NN + 255)/256, 3);
  int agrid = (NN + 3)/4;

  // ----- layer 0 -----
  g.astride = DD;
  g.A[0]=e_emb; g.A[1]=b_emb; g.A[2]=s_emb;
  g.W[0]=e_W;   g.W[1]=b_W;   g.W[2]=s_W;
  g.Bias[0]=e_b; g.Bias[1]=b_b; g.Bias[2]=s_b;
  k_gemm<<<ggrid, 256, 0, stream>>>(g);
  k_agg <<<agrid, 256, 0, stream>>>(a);

  // ----- layer 1 (reads d_out strided, overwrites d_out) -----
  g.astride = 3*DD;
  g.A[0]=out; g.A[1]=out+DD; g.A[2]=out+2*DD;
  g.W[0]=e_W+DD*DD; g.W[1]=b_W+DD*DD; g.W[2]=s_W+DD*DD;
  g.Bias[0]=e_b+DD; g.Bias[1]=b_b+DD; g.Bias[2]=s_b+DD;
  k_gemm<<<ggrid, 256, 0, stream>>>(g);
  k_agg <<<agrid, 256, 0, stream>>>(a);
}

// Round 4
// 539.082 us; speedup vs baseline: 1.9311x; 1.1488x over previous
//
#include <hip/hip_runtime.h>
#include <hip/hip_bf16.h>

#define NN 50000
#define NE 800000
#define DD 128

typedef unsigned int u32;
typedef __attribute__((ext_vector_type(8))) short short8;   // 8 bf16 = 4 VGPRs
typedef __attribute__((ext_vector_type(4))) float f32x4;
typedef __attribute__((ext_vector_type(4))) u32 u32x4;

__device__ __forceinline__ u32 f2bf2(float a, float b){
  union { __hip_bfloat162 h; u32 u; } cv;
  cv.h = __float22bfloat162_rn(make_float2(a, b));   // v_cvt_pk_bf16_f32 on gfx950
  return cv.u;
}
__device__ __forceinline__ float blo(u32 v){ return __uint_as_float(v << 16); }
__device__ __forceinline__ float bhi(u32 v){ return __uint_as_float(v & 0xffff0000u); }

// ---------------- weight prep: fp32 W -> frag-ordered bf16 (once per launch) ------
// frag (ct,ks) of mat: lane holds W[ct*16+rr][ks*32+quad*8+j], j=0..7 (16 B)
struct PrepArgs { const float* W[6]; u32* out; };
__global__ __launch_bounds__(256) void k_prep(PrepArgs pa){
  int tid = blockIdx.x*256 + threadIdx.x;        // 6 mats * 32 frags * 64 lanes
  int mat = tid >> 11, rem = tid & 2047;
  int frag = rem >> 6, lane = rem & 63;
  int ct = frag >> 2, ks = frag & 3, rr = lane & 15, quad = lane >> 4;
  const float* p = pa.W[mat] + (ct*16 + rr)*128 + ks*32 + quad*8;
  float4 f0 = *(const float4*)p;
  float4 f1 = *(const float4*)(p + 4);
  u32x4 q;
  q.x = f2bf2(f0.x, f0.y); q.y = f2bf2(f0.z, f0.w);
  q.z = f2bf2(f1.x, f1.y); q.w = f2bf2(f1.z, f1.w);
  *(u32x4*)(pa.out + (size_t)tid*4) = q;
}

// ---------------- CSR build ----------------
__global__ void k_hist(const int* __restrict__ dst, int* __restrict__ cnt){
  int i = blockIdx.x*256 + threadIdx.x;
  if (i < NE) atomicAdd(&cnt[dst[i]], 1);
}

__global__ __launch_bounds__(1024) void k_scan(const int* __restrict__ cnt,
                                               int* __restrict__ row_start,
                                               int* __restrict__ cursor){
  __shared__ int wsum[16];
  __shared__ int carry;
  const int t = threadIdx.x, lane = t & 63, wid = t >> 6;
  if (t == 0) carry = 0;
  __syncthreads();
  for (int base = 0; base < NN; base += 1024){
    int i = base + t;
    int v = (i < NN) ? cnt[i] : 0;
    int incl = v;
    #pragma unroll
    for (int off = 1; off < 64; off <<= 1){
      int u = __shfl_up(incl, off, 64);
      if (lane >= off) incl += u;
    }
    if (lane == 63) wsum[wid] = incl;
    __syncthreads();
    if (wid == 0){
      int w = (lane < 16) ? wsum[lane] : 0;
      #pragma unroll
      for (int off = 1; off < 16; off <<= 1){
        int u = __shfl_up(w, off, 64);
        if (lane >= off) w += u;
      }
      if (lane < 16) wsum[lane] = w;
    }
    __syncthreads();
    int woff = (wid > 0) ? wsum[wid-1] : 0;
    int excl = carry + woff + (incl - v);
    if (i < NN){ row_start[i] = excl; cursor[i] = excl; }
    __syncthreads();
    if (t == 0) carry += wsum[15];
    __syncthreads();
  }
  if (t == 0) row_start[NN] = carry;
}

__global__ void k_scatter(const int* __restrict__ src, const int* __restrict__ dst,
                          int* __restrict__ cursor, int* __restrict__ esrc){
  int i = blockIdx.x*256 + threadIdx.x;
  if (i < NE){
    int d = dst[i];
    int p = atomicAdd(&cursor[d], 1);
    esrc[p] = src[i];
  }
}

// ------------- fused pre-transform + bf16-MFMA GEMM, barrier-free streaming -------
// W (frag-packed bf16) in 32 KB LDS per block; each wave loads its own 16 A-rows
// straight into MFMA B-frag registers; grid-stride over 3125 groups per manifold.
struct GemmArgs {
  const float* A[3];
  const float* Bias[3];
  const u32* Wf;          // frag-packed weights for this layer (3 mats)
  u32* H;                 // manifold m at H + m*NN*64
  const float* curv;
  int astride;
};

__global__ __launch_bounds__(256,3) void k_gemm(GemmArgs ga){
  const int m = blockIdx.y;
  const float* __restrict__ A    = ga.A[m];
  const float* __restrict__ Bias = ga.Bias[m];
  u32* __restrict__ H = ga.H + (size_t)m*NN*64;
  const int astride = ga.astride;
  const int t = threadIdx.x;
  const int lane = t & 63;
  const int rr = lane & 15, quad = lane >> 4;

  __shared__ u32 Wlds[8192];        // 32 frags x 64 lanes x 16 B, conflict-free b128
  {
    const u32x4* wsrc = (const u32x4*)(ga.Wf + (size_t)m*8192);
    #pragma unroll
    for (int it = 0; it < 8; ++it){
      int idx = it*256 + t;
      *(u32x4*)&Wlds[idx*4] = wsrc[idx];
    }
  }
  __syncthreads();                  // the only barrier in the kernel

  float sc = 1.f;
  if (m == 1) sc = sqrtf(*ga.curv);

  const int nw = gridDim.x * 4;
  for (int g = blockIdx.x*4 + (t >> 6); g < 3125; g += nw){
    // ---- load 16 rows into B-frag layout: lane(rr,quad) = row rr, k quad*8.. ----
    const float* ap = A + (size_t)(g*16 + rr)*astride + quad*8;
    float4 c[8];
    #pragma unroll
    for (int ks = 0; ks < 4; ++ks){
      c[2*ks]   = *(const float4*)(ap + ks*32);
      c[2*ks+1] = *(const float4*)(ap + ks*32 + 4);
    }
    // ---- row-norm pre-transform (register shuffles, no LDS) ----
    if (m != 0){
      float p = 0.f;
      #pragma unroll
      for (int i = 0; i < 8; ++i)
        p += c[i].x*c[i].x + c[i].y*c[i].y + c[i].z*c[i].z + c[i].w*c[i].w;
      p += __shfl_xor(p, 16, 64);
      p += __shfl_xor(p, 32, 64);
      float nrm = sqrtf(p);
      float sca;
      if (m == 1){    // log-map at origin: (2/sc)*artanh(sc*|y|)/|y|
        float x = sc * nrm;
        sca = (nrm > 1e-30f) ? (logf((1.f + x)/(1.f - x)) / (sc * nrm)) : 2.f;
      } else {        // l2norm
        sca = 1.f / fmaxf(nrm, 1e-12f);
      }
      #pragma unroll
      for (int i = 0; i < 8; ++i){ c[i].x*=sca; c[i].y*=sca; c[i].z*=sca; c[i].w*=sca; }
    }
    // ---- pack to bf16 frags + MFMA (W a-frags re-read from LDS) ----
    f32x4 acc[8];
    #pragma unroll
    for (int ct = 0; ct < 8; ++ct){ f32x4 z = {0.f,0.f,0.f,0.f}; acc[ct] = z; }
    #pragma unroll
    for (int ks = 0; ks < 4; ++ks){
      u32x4 bq;
      bq.x = f2bf2(c[2*ks].x,   c[2*ks].y);
      bq.y = f2bf2(c[2*ks].z,   c[2*ks].w);
      bq.z = f2bf2(c[2*ks+1].x, c[2*ks+1].y);
      bq.w = f2bf2(c[2*ks+1].z, c[2*ks+1].w);
      short8 bf = __builtin_bit_cast(short8, bq);
      #pragma unroll
      for (int ct = 0; ct < 8; ++ct){
        short8 wf = *(const short8*)&Wlds[((ct*4 + ks)*64 + lane)*4];
        acc[ct] = __builtin_amdgcn_mfma_f32_16x16x32_bf16(wf, bf, acc[ct], 0, 0, 0);
      }
    }
    // ---- epilogue: bias (+ spherical l2norm), bf16 pack, store ----
    #pragma unroll
    for (int ct = 0; ct < 8; ++ct){
      float4 bv = *(const float4*)(Bias + ct*16 + quad*4);
      acc[ct].x += bv.x; acc[ct].y += bv.y; acc[ct].z += bv.z; acc[ct].w += bv.w;
    }
    if (m == 2){
      float p = 0.f;
      #pragma unroll
      for (int ct = 0; ct < 8; ++ct)
        p += acc[ct].x*acc[ct].x + acc[ct].y*acc[ct].y + acc[ct].z*acc[ct].z + acc[ct].w*acc[ct].w;
      p += __shfl_xor(p, 16, 64);
      p += __shfl_xor(p, 32, 64);
      float inv = 1.f / fmaxf(sqrtf(p), 1e-12f);
      #pragma unroll
      for (int ct = 0; ct < 8; ++ct){ acc[ct].x*=inv; acc[ct].y*=inv; acc[ct].z*=inv; acc[ct].w*=inv; }
    }
    u32* hp = H + (size_t)(g*16 + rr)*64 + quad*2;   // channel = ct*16 + quad*4 + reg
    #pragma unroll
    for (int ct = 0; ct < 8; ++ct){
      uint2 pk;
      pk.x = f2bf2(acc[ct].x, acc[ct].y);
      pk.y = f2bf2(acc[ct].z, acc[ct].w);
      *(uint2*)(hp + ct*8) = pk;
    }
  }
}

// ------- mean-aggregate + post-transform; one wave per node, 2 edges per pass -----
// lanes 0-31 handle even pair-edge, 32-63 odd; each lane owns 4 features (8 B).
struct AggArgs {
  const u32* H;
  float* O;
  const int* row_start;
  const int* esrc;
  const float* curv;
};

__global__ __launch_bounds__(256) void k_agg(AggArgs aa){
  const int tid = threadIdx.x;
  const int lane = tid & 63;
  const int half = lane >> 5, hl = lane & 31;
  const int node = blockIdx.x*4 + (tid >> 6);
  if (node >= NN) return;
  const int e0 = aa.row_start[node], e1 = aa.row_start[node+1];
  const int* __restrict__ esrc = aa.esrc;
  const u32* __restrict__ h0 = aa.H;
  const u32* __restrict__ h1 = aa.H + (size_t)NN*64;
  const u32* __restrict__ h2 = aa.H + (size_t)2*NN*64;
  const int fo = hl*2;

  float a0[4] = {0.f,0.f,0.f,0.f};
  float a1[4] = {0.f,0.f,0.f,0.f};
  float a2[4] = {0.f,0.f,0.f,0.f};

  for (int base = e0; base < e1; base += 64){
    int nn = e1 - base; if (nn > 64) nn = 64;
    int sv = esrc[min(base + lane, e1 - 1)];   // 64 edge indices, one coalesced load
    int np = (nn + 1) >> 1;
    int p = 0;
    for (; p + 4 <= np; p += 4){               // 8 edges, 12 dwordx2 gathers in flight
      uint2 q[4][3]; float w[4];
      #pragma unroll
      for (int u = 0; u < 4; ++u){
        int idx = 2*(p + u) + half;
        w[u] = (idx < nn) ? 1.f : 0.f;
        int s = __shfl(sv, min(idx, nn - 1), 64);
        size_t off = (size_t)s*64 + fo;
        q[u][0] = *(const uint2*)(h0 + off);
        q[u][1] = *(const uint2*)(h1 + off);
        q[u][2] = *(const uint2*)(h2 + off);
      }
      #pragma unroll
      for (int u = 0; u < 4; ++u){
        a0[0] += w[u]*blo(q[u][0].x); a0[1] += w[u]*bhi(q[u][0].x);
        a0[2] += w[u]*blo(q[u][0].y); a0[3] += w[u]*bhi(q[u][0].y);
        a1[0] += w[u]*blo(q[u][1].x); a1[1] += w[u]*bhi(q[u][1].x);
        a1[2] += w[u]*blo(q[u][1].y); a1[3] += w[u]*bhi(q[u][1].y);
        a2[0] += w[u]*blo(q[u][2].x); a2[1] += w[u]*bhi(q[u][2].x);
        a2[2] += w[u]*blo(q[u][2].y); a2[3] += w[u]*bhi(q[u][2].y);
      }
    }
    for (; p < np; ++p){
      int idx = 2*p + half;
      float w = (idx < nn) ? 1.f : 0.f;
      int s = __shfl(sv, min(idx, nn - 1), 64);
      size_t off = (size_t)s*64 + fo;
      uint2 q0 = *(const uint2*)(h0 + off);
      uint2 q1 = *(const uint2*)(h1 + off);
      uint2 q2 = *(const uint2*)(h2 + off);
      a0[0] += w*blo(q0.x); a0[1] += w*bhi(q0.x); a0[2] += w*blo(q0.y); a0[3] += w*bhi(q0.y);
      a1[0] += w*blo(q1.x); a1[1] += w*bhi(q1.x); a1[2] += w*blo(q1.y); a1[3] += w*bhi(q1.y);
      a2[0] += w*blo(q2.x); a2[1] += w*bhi(q2.x); a2[2] += w*blo(q2.y); a2[3] += w*bhi(q2.y);
    }
  }

  // combine the two half-wave edge partitions
  #pragma unroll
  for (int j = 0; j < 4; ++j){
    a0[j] += __shfl_xor(a0[j], 32, 64);
    a1[j] += __shfl_xor(a1[j], 32, 64);
    a2[j] += __shfl_xor(a2[j], 32, 64);
  }
  float inv = 1.f / (float)max(e1 - e0, 1);
  #pragma unroll
  for (int j = 0; j < 4; ++j){ a0[j]*=inv; a1[j]*=inv; a2[j]*=inv; }

  float p1 = a1[0]*a1[0] + a1[1]*a1[1] + a1[2]*a1[2] + a1[3]*a1[3];
  float p2 = a2[0]*a2[0] + a2[1]*a2[1] + a2[2]*a2[2] + a2[3]*a2[3];
  #pragma unroll
  for (int off = 1; off < 32; off <<= 1){
    p1 += __shfl_xor(p1, off, 64);
    p2 += __shfl_xor(p2, off, 64);
  }
  float n1 = sqrtf(p1);
  float scv = sqrtf(*aa.curv);
  float x = scv * n1;
  float s1 = (n1 > 1e-30f) ? (tanhf(0.5f*x) / x) : 0.5f;   // exp-map at origin
  float s2 = 1.f / fmaxf(sqrtf(p2), 1e-12f);               // l2norm

  float* op = aa.O + (size_t)node*384;
  if (half == 0){
    float4 e4 = make_float4(a0[0] > 0.f ? a0[0] : 0.2f*a0[0],
                            a0[1] > 0.f ? a0[1] : 0.2f*a0[1],
                            a0[2] > 0.f ? a0[2] : 0.2f*a0[2],
                            a0[3] > 0.f ? a0[3] : 0.2f*a0[3]);
    *(float4*)(op + hl*4) = e4;
    *(float4*)(op + 128 + hl*4) = make_float4(a1[0]*s1, a1[1]*s1, a1[2]*s1, a1[3]*s1);
  } else {
    *(float4*)(op + 256 + hl*4) = make_float4(a2[0]*s2, a2[1]*s2, a2[2]*s2, a2[3]*s2);
  }
}

extern "C" void kernel_launch(void* const* d_in, const int* in_sizes, int n_in,
                              void* d_out, int out_size, void* d_ws, size_t ws_size,
                              hipStream_t stream){
  (void)in_sizes; (void)n_in; (void)out_size; (void)ws_size;
  const int*   src    = (const int*)  d_in[0];
  const int*   dst    = (const int*)  d_in[1];
  const float* e_emb  = (const float*)d_in[2];
  const float* b_emb  = (const float*)d_in[3];
  const float* s_emb  = (const float*)d_in[4];
  const float* e_W    = (const float*)d_in[5];
  const float* e_b    = (const float*)d_in[6];
  const float* b_W    = (const float*)d_in[7];
  const float* b_b    = (const float*)d_in[8];
  const float* s_W    = (const float*)d_in[9];
  const float* s_b    = (const float*)d_in[10];
  const float* b_curv = (const float*)d_in[11];
  float* out = (float*)d_out;

  char* ws = (char*)d_ws;
  size_t off = 0;
  auto alloc = [&](size_t bytes) -> void* {
    void* p = (void*)(ws + off);
    off += (bytes + 255) & ~(size_t)255;
    return p;
  };
  int* cnt       = (int*)alloc((size_t)NN*4);
  int* row_start = (int*)alloc((size_t)(NN+1)*4);
  int* cursor    = (int*)alloc((size_t)NN*4);
  int* esrc      = (int*)alloc((size_t)NE*4);
  u32* h         = (u32*)alloc((size_t)3*NN*64*4);
  u32* wf        = (u32*)alloc((size_t)6*2048*16);   // frag-packed bf16 weights

  (void)hipMemsetAsync(cnt, 0, (size_t)NN*4, stream);

  PrepArgs pp;
  pp.W[0] = e_W;          pp.W[1] = b_W;          pp.W[2] = s_W;
  pp.W[3] = e_W + 16384;  pp.W[4] = b_W + 16384;  pp.W[5] = s_W + 16384;
  pp.out = wf;
  k_prep   <<<48, 256, 0, stream>>>(pp);

  k_hist   <<<NE/256, 256, 0, stream>>>(dst, cnt);
  k_scan   <<<1, 1024, 0, stream>>>(cnt, row_start, cursor);
  k_scatter<<<NE/256, 256, 0, stream>>>(src, dst, cursor, esrc);

  GemmArgs g;
  g.H = h; g.curv = b_curv;
  AggArgs a;
  a.H = h; a.O = out; a.row_start = row_start; a.esrc = esrc; a.curv = b_curv;

  dim3 ggrid(157, 3);          // 628 waves per manifold
  int agrid = (NN + 3)/4;

  // ----- layer 0 -----
  g.astride = DD;
  g.A[0]=e_emb; g.A[1]=b_emb; g.A[2]=s_emb;
  g.Bias[0]=e_b; g.Bias[1]=b_b; g.Bias[2]=s_b;
  g.Wf = wf;
  k_gemm<<<ggrid, 256, 0, stream>>>(g);
  k_agg <<<agrid, 256, 0, stream>>>(a);

  // ----- layer 1 (reads d_out strided, overwrites d_out) -----
  g.astride = 3*DD;
  g.A[0]=out; g.A[1]=out+DD; g.A[2]=out+2*DD;
  g.Bias[0]=e_b+DD; g.Bias[1]=b_b+DD; g.Bias[2]=s_b+DD;
  g.Wf = wf + 3*8192;
  k_gemm<<<ggrid, 256, 0, stream>>>(g);
  k_agg <<<agrid, 256, 0, stream>>>(a);
}